// Round 5
// baseline (339.577 us; speedup 1.0000x reference)
//
#include <hip/hip_runtime.h>
#include <hip/hip_bf16.h>

#define NNODES 50000
#define NEDGES 640000
#define NGRAPH 64
#define HD     128

typedef __attribute__((ext_vector_type(8))) short short8;
typedef __attribute__((ext_vector_type(4))) float f32x4;

__device__ __forceinline__ float uf(uint u) { return __uint_as_float(u); }
// fp32 -> bf16 round-to-nearest-even
__device__ __forceinline__ ushort f2b(float f) {
    uint u = __float_as_uint(f);
    return (ushort)((u + 0x7fffu + ((u >> 16) & 1u)) >> 16);
}

// ---------------------------------------------------------------------------
// wpinit: pack 5 fp32 128x128 weights into bf16 MFMA B-fragment order,
// AND zero count[] + pooled[] (grid-stride over the dim3(8,5) x 256 grid).
// ---------------------------------------------------------------------------
__global__ __launch_bounds__(256) void wpinit_k(const float* __restrict__ W0,
                                                const float* __restrict__ W1,
                                                const float* __restrict__ W2,
                                                const float* __restrict__ W3,
                                                const float* __restrict__ W4,
                                                ushort* __restrict__ Wp,
                                                int* __restrict__ count,
                                                float* __restrict__ pooled) {
    int which = blockIdx.y;
    const float* W = (which == 0) ? W0 : (which == 1) ? W1 : (which == 2) ? W2
                   : (which == 3) ? W3 : W4;
    ushort* dst = Wp + (size_t)which * 16384;
    int idx = blockIdx.x * 256 + threadIdx.x;   // 0..2047
    int l  = idx & 63;
    int kt = (idx >> 6) & 3;
    int nt = idx >> 8;
    int krow = kt * 32 + (l >> 4) * 8;
    int col  = nt * 16 + (l & 15);
    short8 v;
#pragma unroll
    for (int j = 0; j < 8; ++j) v[j] = (short)f2b(W[(size_t)(krow + j) * HD + col]);
    *(short8*)(dst + ((size_t)(nt * 4 + kt) * 64 + l) * 8) = v;
    // zeroing: flat id over 10240 threads
    int fid = (blockIdx.y * 8 + blockIdx.x) * 256 + threadIdx.x;
    for (int i = fid; i < NNODES; i += 10240) count[i] = 0;
    for (int i = fid; i < NGRAPH * 384; i += 10240) pooled[i] = 0.f;
}

// ---------------------------------------------------------------------------
// CSR build: histogram -> single-block scan -> scatter
// ---------------------------------------------------------------------------
__global__ __launch_bounds__(256) void hist_k(const int* __restrict__ dst,
                                              int* __restrict__ count, int E) {
    int e = blockIdx.x * 256 + threadIdx.x;
    if (e < E) atomicAdd(&count[dst[e]], 1);
}

// single 1024-thread block scans all N counts (N small: 50000)
__global__ __launch_bounds__(1024) void scan_k(const int* __restrict__ count,
                                               int* __restrict__ row_start,
                                               int* __restrict__ cur, int N, int E) {
    __shared__ int s[1024];
    int t = threadIdx.x;
    const int CH = (N + 1023) / 1024;          // 49
    int base = t * CH;
    int sum = 0;
    for (int i = 0; i < CH; ++i) {
        int idx = base + i;
        if (idx < N) sum += count[idx];
    }
    s[t] = sum;
    __syncthreads();
    for (int off = 1; off < 1024; off <<= 1) {
        int v = s[t];
        if (t >= off) v += s[t - off];
        __syncthreads();
        s[t] = v;
        __syncthreads();
    }
    int pre = (t == 0) ? 0 : s[t - 1];
    for (int i = 0; i < CH; ++i) {
        int idx = base + i;
        if (idx < N) {
            row_start[idx] = pre;
            cur[idx] = pre;
            pre += count[idx];
        }
    }
    if (t == 1023) row_start[N] = E;
}

__global__ __launch_bounds__(256) void scatter_k(const int* __restrict__ src,
                                                 const int* __restrict__ dst,
                                                 int* __restrict__ cur,
                                                 int* __restrict__ nbr, int E) {
    int e = blockIdx.x * 256 + threadIdx.x;
    if (e < E) {
        int d = dst[e];
        int pos = atomicAdd(&cur[d], 1);
        nbr[pos] = src[e];
    }
}

// ---------------------------------------------------------------------------
// bf16 aggregation: out[n] = h[n] + sum_{s in nbr(n)} h[s]   (fp32 accumulate)
// 2 nodes per wave; neighbor walk unrolled x8 for MLP (16 rows in flight/wave).
// ---------------------------------------------------------------------------
__global__ __launch_bounds__(256) void aggb_k(const ushort* __restrict__ h,
                                              const int* __restrict__ row_start,
                                              const int* __restrict__ nbr,
                                              ushort* __restrict__ out, int nNodes) {
    int gw   = (blockIdx.x * 256 + threadIdx.x) >> 6;
    int lane = threadIdx.x & 63;
    int node = gw * 2 + (lane >> 5);
    int sub  = lane & 31;
    if (node >= nNodes) return;
    const uint2* hp = (const uint2*)h;
    uint2 u = hp[(size_t)node * 32 + sub];
    float f0 = uf(u.x << 16), f1 = uf(u.x & 0xffff0000u);
    float f2v = uf(u.y << 16), f3 = uf(u.y & 0xffff0000u);
    int rs = row_start[node], re = row_start[node + 1];
    int p = rs;
#define ACC4(vv) { f0 += uf(vv.x << 16); f1 += uf(vv.x & 0xffff0000u); \
                   f2v += uf(vv.y << 16); f3 += uf(vv.y & 0xffff0000u); }
    for (; p + 8 <= re; p += 8) {
        int s0 = nbr[p],     s1 = nbr[p + 1], s2 = nbr[p + 2], s3 = nbr[p + 3];
        int s4 = nbr[p + 4], s5 = nbr[p + 5], s6 = nbr[p + 6], s7 = nbr[p + 7];
        uint2 v0 = hp[(size_t)s0 * 32 + sub];
        uint2 v1 = hp[(size_t)s1 * 32 + sub];
        uint2 v2 = hp[(size_t)s2 * 32 + sub];
        uint2 v3 = hp[(size_t)s3 * 32 + sub];
        uint2 v4 = hp[(size_t)s4 * 32 + sub];
        uint2 v5 = hp[(size_t)s5 * 32 + sub];
        uint2 v6 = hp[(size_t)s6 * 32 + sub];
        uint2 v7 = hp[(size_t)s7 * 32 + sub];
        ACC4(v0) ACC4(v1) ACC4(v2) ACC4(v3)
        ACC4(v4) ACC4(v5) ACC4(v6) ACC4(v7)
    }
    for (; p + 4 <= re; p += 4) {
        int s0 = nbr[p], s1 = nbr[p + 1], s2 = nbr[p + 2], s3 = nbr[p + 3];
        uint2 v0 = hp[(size_t)s0 * 32 + sub];
        uint2 v1 = hp[(size_t)s1 * 32 + sub];
        uint2 v2 = hp[(size_t)s2 * 32 + sub];
        uint2 v3 = hp[(size_t)s3 * 32 + sub];
        ACC4(v0) ACC4(v1) ACC4(v2) ACC4(v3)
    }
    for (; p < re; ++p) {
        int s = nbr[p];
        uint2 v = hp[(size_t)s * 32 + sub];
        ACC4(v)
    }
#undef ACC4
    uint2 o;
    o.x = (uint)f2b(f0) | ((uint)f2b(f1) << 16);
    o.y = (uint)f2b(f2v) | ((uint)f2b(f3) << 16);
    ((uint2*)out)[(size_t)node * 32 + sub] = o;
}

// ---------------------------------------------------------------------------
// 128x128 bf16 MFMA GEMM step on an LDS tile. In-place safe: wave w only
// reads/writes rows [32w, 32w+32). D = bf16(relu(A @ Wp + bias)).
// ---------------------------------------------------------------------------
__device__ __forceinline__ void gemm128(const ushort* __restrict__ A,
                                        const short8* __restrict__ Wp,
                                        const float* __restrict__ bias,
                                        ushort* __restrict__ D, int tid) {
    const int l = tid & 63, w = tid >> 6;
    const int lr = l & 15, lg = l >> 4;
    const int wbase = w * 32;
    const int sw = lr & 7;
    f32x4 acc[2][8];
    const f32x4 z4 = {0.f, 0.f, 0.f, 0.f};
#pragma unroll
    for (int m = 0; m < 2; ++m)
#pragma unroll
        for (int n = 0; n < 8; ++n) acc[m][n] = z4;
#pragma unroll
    for (int kt = 0; kt < 4; ++kt) {
        const int pch = ((kt * 4 + lg) ^ sw) * 8;
        short8 a0 = *(const short8*)(A + (wbase + lr) * 128 + pch);
        short8 a1 = *(const short8*)(A + (wbase + 16 + lr) * 128 + pch);
#pragma unroll
        for (int n = 0; n < 8; ++n) {
            short8 b = Wp[(n * 4 + kt) * 64 + l];
            acc[0][n] = __builtin_amdgcn_mfma_f32_16x16x32_bf16(a0, b, acc[0][n], 0, 0, 0);
            acc[1][n] = __builtin_amdgcn_mfma_f32_16x16x32_bf16(a1, b, acc[1][n], 0, 0, 0);
        }
    }
#pragma unroll
    for (int n = 0; n < 8; ++n) {
        const int col = n * 16 + lr;
        const float bb = bias[col];
        const int cch = col >> 3, cof = col & 7;
#pragma unroll
        for (int m = 0; m < 2; ++m) {
#pragma unroll
            for (int r = 0; r < 4; ++r) {
                int row = wbase + m * 16 + lg * 4 + r;
                float t = fmaxf(acc[m][n][r] + bb, 0.f);
                D[row * 128 + ((cch ^ (row & 7)) * 8) + cof] = f2b(t);
            }
        }
    }
}

// Segmented pool of the LDS tile into pooled[g*384 + coloff + col].
__device__ __forceinline__ void pool_tile(const ushort* __restrict__ T,
                                          const int* __restrict__ batchl,
                                          float* __restrict__ pooled,
                                          int coloff, int tid) {
    int col = tid & 127, half = tid >> 7;
    int cch = col >> 3, cof = col & 7;
    float pacc = 0.f;
    int curg = -1;
    for (int r = half * 64; r < half * 64 + 64; ++r) {
        int g = batchl[r];
        if (g != curg) {
            if (curg >= 0) atomicAdd(&pooled[curg * 384 + coloff + col], pacc);
            curg = g;
            pacc = 0.f;
        }
        if (g >= 0) pacc += uf((uint)T[r * 128 + ((cch ^ (r & 7)) * 8) + cof] << 16);
    }
    if (curg >= 0) atomicAdd(&pooled[curg * 384 + coloff + col], pacc);
}

// ---------------------------------------------------------------------------
// Fused layer 1: h1 = relu(relu((x + agg(x)) @ W1 + b1) @ W2 + b2) + pool
// ---------------------------------------------------------------------------
__global__ __launch_bounds__(256) void fl1_k(const float* __restrict__ x,
                                             const int* __restrict__ batch,
                                             const int* __restrict__ row_start,
                                             const int* __restrict__ nbr,
                                             const float* __restrict__ W1, // 8x128
                                             const float* __restrict__ b1,
                                             const short8* __restrict__ Wp2,
                                             const float* __restrict__ b2,
                                             ushort* __restrict__ out,
                                             float* __restrict__ pooled, int nNodes) {
    __shared__ float hin[128][8];
    __shared__ __align__(16) ushort T[128 * 128];
    __shared__ int batchl[128];
    int t = threadIdx.x;
    int n0 = blockIdx.x * 128;
    if (t < 128) batchl[t] = (n0 + t < nNodes) ? batch[n0 + t] : -1;
    {   // gather-sum staging: 2 threads per row, unroll x8
        int r = t >> 1;
        int half = t & 1;
        int n = n0 + r;
        float4 v = make_float4(0.f, 0.f, 0.f, 0.f);
        if (n < nNodes) {
            v = *(const float4*)(x + (size_t)n * 8 + half * 4);
            int rs = row_start[n], re = row_start[n + 1];
            int p = rs;
#define AX(u) { v.x += u.x; v.y += u.y; v.z += u.z; v.w += u.w; }
            for (; p + 8 <= re; p += 8) {
                int s0 = nbr[p],     s1 = nbr[p + 1], s2 = nbr[p + 2], s3 = nbr[p + 3];
                int s4 = nbr[p + 4], s5 = nbr[p + 5], s6 = nbr[p + 6], s7 = nbr[p + 7];
                float4 u0 = *(const float4*)(x + (size_t)s0 * 8 + half * 4);
                float4 u1 = *(const float4*)(x + (size_t)s1 * 8 + half * 4);
                float4 u2 = *(const float4*)(x + (size_t)s2 * 8 + half * 4);
                float4 u3 = *(const float4*)(x + (size_t)s3 * 8 + half * 4);
                float4 u4 = *(const float4*)(x + (size_t)s4 * 8 + half * 4);
                float4 u5 = *(const float4*)(x + (size_t)s5 * 8 + half * 4);
                float4 u6 = *(const float4*)(x + (size_t)s6 * 8 + half * 4);
                float4 u7 = *(const float4*)(x + (size_t)s7 * 8 + half * 4);
                AX(u0) AX(u1) AX(u2) AX(u3) AX(u4) AX(u5) AX(u6) AX(u7)
            }
            for (; p < re; ++p) {
                int s = nbr[p];
                float4 u = *(const float4*)(x + (size_t)s * 8 + half * 4);
                AX(u)
            }
#undef AX
        }
        *(float4*)(&hin[r][half * 4]) = v;
    }
    __syncthreads();
    // MLP1 (8->128), bf16 result into swizzled T
    int tx = t & 15, ty = t >> 4;
    float w[8][8];
#pragma unroll
    for (int k = 0; k < 8; ++k) {
        float4 w0 = *(const float4*)(W1 + k * HD + tx * 8);
        float4 w1 = *(const float4*)(W1 + k * HD + tx * 8 + 4);
        w[k][0] = w0.x; w[k][1] = w0.y; w[k][2] = w0.z; w[k][3] = w0.w;
        w[k][4] = w1.x; w[k][5] = w1.y; w[k][6] = w1.z; w[k][7] = w1.w;
    }
    float4 c0 = *(const float4*)(b1 + tx * 8);
    float4 c1 = *(const float4*)(b1 + tx * 8 + 4);
    float bb[8] = {c0.x, c0.y, c0.z, c0.w, c1.x, c1.y, c1.z, c1.w};
#pragma unroll
    for (int i = 0; i < 8; ++i) {
        int r = ty * 8 + i;
        float4 a0 = *(const float4*)(&hin[r][0]);
        float4 a1 = *(const float4*)(&hin[r][4]);
        float a[8] = {a0.x, a0.y, a0.z, a0.w, a1.x, a1.y, a1.z, a1.w};
        short8 ov;
#pragma unroll
        for (int jj = 0; jj < 8; ++jj) {
            float acc = bb[jj];
#pragma unroll
            for (int k = 0; k < 8; ++k) acc += a[k] * w[k][jj];
            ov[jj] = (short)f2b(fmaxf(acc, 0.f));
        }
        *(short8*)(T + r * 128 + ((tx ^ (r & 7)) * 8)) = ov;
    }
    __syncthreads();
    gemm128(T, Wp2, b2, T, t);     // in-place, wave-private rows
    __syncthreads();
#pragma unroll
    for (int i = 0; i < 8; ++i) {
        int idx = i * 256 + t;
        int row = idx >> 4, ch = idx & 15;
        int n = n0 + row;
        if (n < nNodes) {
            short8 v = *(const short8*)(T + row * 128 + ((ch ^ (row & 7)) * 8));
            *(short8*)(out + (size_t)n * HD + ch * 8) = v;
        }
    }
    pool_tile(T, batchl, pooled, 0, t);
}

// ---------------------------------------------------------------------------
// Fused layer MLP (layers 2,3): out = relu(relu(A@W1+b1)@W2+b2) + pool.
// STORE=0 skips the global h-store (layer 3: pool is the only consumer).
// ---------------------------------------------------------------------------
template <int STORE>
__global__ __launch_bounds__(256) void fmm_k(const ushort* __restrict__ Ain,
                                             const int* __restrict__ batch,
                                             const short8* __restrict__ Wp1,
                                             const float* __restrict__ b1,
                                             const short8* __restrict__ Wp2,
                                             const float* __restrict__ b2,
                                             ushort* __restrict__ out,
                                             float* __restrict__ pooled,
                                             int coloff, int nNodes) {
    __shared__ __align__(16) ushort T[128 * 128];
    __shared__ int batchl[128];
    const int t = threadIdx.x;
    const int n0 = blockIdx.x * 128;
    if (t < 128) batchl[t] = (n0 + t < nNodes) ? batch[n0 + t] : -1;
#pragma unroll
    for (int i = 0; i < 8; ++i) {
        int idx = i * 256 + t;
        int row = idx >> 4, ch = idx & 15;
        short8 v = {0, 0, 0, 0, 0, 0, 0, 0};
        int n = n0 + row;
        if (n < nNodes) v = *(const short8*)(Ain + (size_t)n * HD + ch * 8);
        *(short8*)(T + row * 128 + ((ch ^ (row & 7)) * 8)) = v;
    }
    __syncthreads();
    gemm128(T, Wp1, b1, T, t);
    __syncthreads();
    gemm128(T, Wp2, b2, T, t);
    __syncthreads();
    if constexpr (STORE) {
#pragma unroll
        for (int i = 0; i < 8; ++i) {
            int idx = i * 256 + t;
            int row = idx >> 4, ch = idx & 15;
            int n = n0 + row;
            if (n < nNodes) {
                short8 v = *(const short8*)(T + row * 128 + ((ch ^ (row & 7)) * 8));
                *(short8*)(out + (size_t)n * HD + ch * 8) = v;
            }
        }
    }
    pool_tile(T, batchl, pooled, coloff, t);
}

// ---------------------------------------------------------------------------
// Classifier (all fp32)
// ---------------------------------------------------------------------------
__global__ __launch_bounds__(256) void cls_k(const float* __restrict__ pooled,
                                             const float* __restrict__ W1,  // 384x256
                                             const float* __restrict__ b1,
                                             const float* __restrict__ gamma,
                                             const float* __restrict__ beta,
                                             const float* __restrict__ mean,
                                             const float* __restrict__ var,
                                             const float* __restrict__ W2,  // 256x4
                                             const float* __restrict__ b2,
                                             float* __restrict__ out) {
    __shared__ float pg[384];
    __shared__ float z[256];
    int g = blockIdx.x, j = threadIdx.x;
    pg[j] = pooled[g * 384 + j];
    if (j < 128) pg[256 + j] = pooled[g * 384 + 256 + j];
    __syncthreads();
    float acc = b1[j];
    for (int k = 0; k < 384; ++k) acc += pg[k] * W1[k * 256 + j];
    acc = (acc - mean[j]) * rsqrtf(var[j] + 1e-5f) * gamma[j] + beta[j];
    z[j] = fmaxf(acc, 0.f);
    __syncthreads();
    if (j < 4) {
        float o = b2[j];
        for (int k = 0; k < 256; ++k) o += z[k] * W2[k * 4 + j];
        out[g * 4 + j] = o;
    }
}

// ---------------------------------------------------------------------------
extern "C" void kernel_launch(void* const* d_in, const int* in_sizes, int n_in,
                              void* d_out, int out_size, void* d_ws, size_t ws_size,
                              hipStream_t stream) {
    const int N = NNODES, E = NEDGES;
    const float* x     = (const float*)d_in[0];
    const int*   ei    = (const int*)d_in[1];
    const int*   batch = (const int*)d_in[2];
    const float* l1W1 = (const float*)d_in[3];
    const float* l1b1 = (const float*)d_in[4];
    const float* l1W2 = (const float*)d_in[5];
    const float* l1b2 = (const float*)d_in[6];
    const float* l2W1 = (const float*)d_in[7];
    const float* l2b1 = (const float*)d_in[8];
    const float* l2W2 = (const float*)d_in[9];
    const float* l2b2 = (const float*)d_in[10];
    const float* l3W1 = (const float*)d_in[11];
    const float* l3b1 = (const float*)d_in[12];
    const float* l3W2 = (const float*)d_in[13];
    const float* l3b2 = (const float*)d_in[14];
    const float* cW1  = (const float*)d_in[15];
    const float* cb1  = (const float*)d_in[16];
    const float* bnG  = (const float*)d_in[17];
    const float* bnB  = (const float*)d_in[18];
    const float* bnM  = (const float*)d_in[19];
    const float* bnV  = (const float*)d_in[20];
    const float* cW2  = (const float*)d_in[21];
    const float* cb2  = (const float*)d_in[22];

    const int* src = ei;
    const int* dst = ei + E;

    // ---- workspace layout ----
    char* wsp = (char*)d_ws;
    ushort* tmpb = (ushort*)wsp;  wsp += (size_t)N * HD * 2;
    ushort* h1   = (ushort*)wsp;  wsp += (size_t)N * HD * 2;
    ushort* h2   = (ushort*)wsp;  wsp += (size_t)N * HD * 2;
    float* pooled = (float*)wsp;  wsp += (size_t)64 * 384 * 4;
    ushort* wp    = (ushort*)wsp; wsp += (size_t)5 * 16384 * 2;
    int* count    = (int*)wsp;    wsp += (size_t)N * 4;
    int* row_start = (int*)wsp;   wsp += (size_t)(N + 1) * 4;
    int* cur       = (int*)wsp;   wsp += (size_t)N * 4;
    int* nbr       = (int*)wsp;   wsp += (size_t)E * 4;

    // setup: weight pack + zero count/pooled, then CSR build
    wpinit_k<<<dim3(8, 5), 256, 0, stream>>>(l1W2, l2W1, l2W2, l3W1, l3W2,
                                             wp, count, pooled);
    hist_k<<<(E + 255) / 256, 256, 0, stream>>>(dst, count, E);
    scan_k<<<1, 1024, 0, stream>>>(count, row_start, cur, N, E);
    scatter_k<<<(E + 255) / 256, 256, 0, stream>>>(src, dst, cur, nbr, E);

    const short8* Wp0 = (const short8*)(wp);
    const short8* Wp1 = (const short8*)(wp + 16384);
    const short8* Wp2 = (const short8*)(wp + 2 * 16384);
    const short8* Wp3 = (const short8*)(wp + 3 * 16384);
    const short8* Wp4 = (const short8*)(wp + 4 * 16384);

    const int mb = (N + 127) / 128;              // 391 tiles
    const int ab = ((N + 1) / 2 * 64) / 256;     // 6250 blocks
    // layer 1 (gather + MLP1 + GEMM2 + pool fused)
    fl1_k<<<mb, 256, 0, stream>>>(x, batch, row_start, nbr, l1W1, l1b1, Wp0, l1b2,
                                  h1, pooled, N);
    // layer 2
    aggb_k<<<ab, 256, 0, stream>>>(h1, row_start, nbr, tmpb, N);
    fmm_k<1><<<mb, 256, 0, stream>>>(tmpb, batch, Wp1, l2b1, Wp2, l2b2, h2,
                                     pooled, 128, N);
    // layer 3 (no h3 store: pool is the only consumer)
    aggb_k<<<ab, 256, 0, stream>>>(h2, row_start, nbr, tmpb, N);
    fmm_k<0><<<mb, 256, 0, stream>>>(tmpb, batch, Wp3, l3b1, Wp4, l3b2, nullptr,
                                     pooled, 256, N);
    // classifier
    cls_k<<<NGRAPH, 256, 0, stream>>>(pooled, cW1, cb1, bnG, bnB, bnM, bnV, cW2, cb2,
                                      (float*)d_out);
}

// Round 6
// 338.845 us; speedup vs baseline: 1.0022x; 1.0022x over previous
//
#include <hip/hip_runtime.h>
#include <hip/hip_bf16.h>

#define NNODES 50000
#define NEDGES 640000
#define NGRAPH 64
#define HD     128

typedef __attribute__((ext_vector_type(8))) short short8;
typedef __attribute__((ext_vector_type(4))) float f32x4;

__device__ __forceinline__ float uf(uint u) { return __uint_as_float(u); }
// fp32 -> bf16 round-to-nearest-even
__device__ __forceinline__ ushort f2b(float f) {
    uint u = __float_as_uint(f);
    return (ushort)((u + 0x7fffu + ((u >> 16) & 1u)) >> 16);
}

// ---------------------------------------------------------------------------
// wpinit: pack 5 fp32 128x128 weights into bf16 MFMA B-fragment order,
// AND zero count[] + pooled[] (grid-stride over the dim3(8,5) x 256 grid).
// ---------------------------------------------------------------------------
__global__ __launch_bounds__(256) void wpinit_k(const float* __restrict__ W0,
                                                const float* __restrict__ W1,
                                                const float* __restrict__ W2,
                                                const float* __restrict__ W3,
                                                const float* __restrict__ W4,
                                                ushort* __restrict__ Wp,
                                                int* __restrict__ count,
                                                float* __restrict__ pooled) {
    int which = blockIdx.y;
    const float* W = (which == 0) ? W0 : (which == 1) ? W1 : (which == 2) ? W2
                   : (which == 3) ? W3 : W4;
    ushort* dst = Wp + (size_t)which * 16384;
    int idx = blockIdx.x * 256 + threadIdx.x;   // 0..2047
    int l  = idx & 63;
    int kt = (idx >> 6) & 3;
    int nt = idx >> 8;
    int krow = kt * 32 + (l >> 4) * 8;
    int col  = nt * 16 + (l & 15);
    short8 v;
#pragma unroll
    for (int j = 0; j < 8; ++j) v[j] = (short)f2b(W[(size_t)(krow + j) * HD + col]);
    *(short8*)(dst + ((size_t)(nt * 4 + kt) * 64 + l) * 8) = v;
    // zeroing: flat id over 10240 threads
    int fid = (blockIdx.y * 8 + blockIdx.x) * 256 + threadIdx.x;
    for (int i = fid; i < NNODES; i += 10240) count[i] = 0;
    for (int i = fid; i < NGRAPH * 384; i += 10240) pooled[i] = 0.f;
}

// ---------------------------------------------------------------------------
// CSR build: histogram -> single-block scan -> scatter
// ---------------------------------------------------------------------------
__global__ __launch_bounds__(256) void hist_k(const int* __restrict__ dst,
                                              int* __restrict__ count, int E) {
    int e = blockIdx.x * 256 + threadIdx.x;
    if (e < E) atomicAdd(&count[dst[e]], 1);
}

// single 1024-thread block scans all N counts (N small: 50000)
__global__ __launch_bounds__(1024) void scan_k(const int* __restrict__ count,
                                               int* __restrict__ row_start,
                                               int* __restrict__ cur, int N, int E) {
    __shared__ int s[1024];
    int t = threadIdx.x;
    const int CH = (N + 1023) / 1024;          // 49
    int base = t * CH;
    int sum = 0;
    for (int i = 0; i < CH; ++i) {
        int idx = base + i;
        if (idx < N) sum += count[idx];
    }
    s[t] = sum;
    __syncthreads();
    for (int off = 1; off < 1024; off <<= 1) {
        int v = s[t];
        if (t >= off) v += s[t - off];
        __syncthreads();
        s[t] = v;
        __syncthreads();
    }
    int pre = (t == 0) ? 0 : s[t - 1];
    for (int i = 0; i < CH; ++i) {
        int idx = base + i;
        if (idx < N) {
            row_start[idx] = pre;
            cur[idx] = pre;
            pre += count[idx];
        }
    }
    if (t == 1023) row_start[N] = E;
}

__global__ __launch_bounds__(256) void scatter_k(const int* __restrict__ src,
                                                 const int* __restrict__ dst,
                                                 int* __restrict__ cur,
                                                 int* __restrict__ nbr, int E) {
    int e = blockIdx.x * 256 + threadIdx.x;
    if (e < E) {
        int d = dst[e];
        int pos = atomicAdd(&cur[d], 1);
        nbr[pos] = src[e];
    }
}

// ---------------------------------------------------------------------------
// bf16 aggregation: out[n] = h[n] + sum_{s in nbr(n)} h[s]   (fp32 accumulate)
// 2 nodes per wave; neighbor walk unrolled x8 for MLP (16 rows in flight/wave).
// ---------------------------------------------------------------------------
__global__ __launch_bounds__(256) void aggb_k(const ushort* __restrict__ h,
                                              const int* __restrict__ row_start,
                                              const int* __restrict__ nbr,
                                              ushort* __restrict__ out, int nNodes) {
    int gw   = (blockIdx.x * 256 + threadIdx.x) >> 6;
    int lane = threadIdx.x & 63;
    int node = gw * 2 + (lane >> 5);
    int sub  = lane & 31;
    if (node >= nNodes) return;
    const uint2* hp = (const uint2*)h;
    uint2 u = hp[(size_t)node * 32 + sub];
    float f0 = uf(u.x << 16), f1 = uf(u.x & 0xffff0000u);
    float f2v = uf(u.y << 16), f3 = uf(u.y & 0xffff0000u);
    int rs = row_start[node], re = row_start[node + 1];
    int p = rs;
#define ACC4(vv) { f0 += uf(vv.x << 16); f1 += uf(vv.x & 0xffff0000u); \
                   f2v += uf(vv.y << 16); f3 += uf(vv.y & 0xffff0000u); }
    for (; p + 8 <= re; p += 8) {
        int s0 = nbr[p],     s1 = nbr[p + 1], s2 = nbr[p + 2], s3 = nbr[p + 3];
        int s4 = nbr[p + 4], s5 = nbr[p + 5], s6 = nbr[p + 6], s7 = nbr[p + 7];
        uint2 v0 = hp[(size_t)s0 * 32 + sub];
        uint2 v1 = hp[(size_t)s1 * 32 + sub];
        uint2 v2 = hp[(size_t)s2 * 32 + sub];
        uint2 v3 = hp[(size_t)s3 * 32 + sub];
        uint2 v4 = hp[(size_t)s4 * 32 + sub];
        uint2 v5 = hp[(size_t)s5 * 32 + sub];
        uint2 v6 = hp[(size_t)s6 * 32 + sub];
        uint2 v7 = hp[(size_t)s7 * 32 + sub];
        ACC4(v0) ACC4(v1) ACC4(v2) ACC4(v3)
        ACC4(v4) ACC4(v5) ACC4(v6) ACC4(v7)
    }
    for (; p + 4 <= re; p += 4) {
        int s0 = nbr[p], s1 = nbr[p + 1], s2 = nbr[p + 2], s3 = nbr[p + 3];
        uint2 v0 = hp[(size_t)s0 * 32 + sub];
        uint2 v1 = hp[(size_t)s1 * 32 + sub];
        uint2 v2 = hp[(size_t)s2 * 32 + sub];
        uint2 v3 = hp[(size_t)s3 * 32 + sub];
        ACC4(v0) ACC4(v1) ACC4(v2) ACC4(v3)
    }
    for (; p < re; ++p) {
        int s = nbr[p];
        uint2 v = hp[(size_t)s * 32 + sub];
        ACC4(v)
    }
#undef ACC4
    uint2 o;
    o.x = (uint)f2b(f0) | ((uint)f2b(f1) << 16);
    o.y = (uint)f2b(f2v) | ((uint)f2b(f3) << 16);
    ((uint2*)out)[(size_t)node * 32 + sub] = o;
}

// ---------------------------------------------------------------------------
// 128x128 bf16 MFMA GEMM step on an LDS tile. In-place safe: wave w only
// reads/writes rows [32w, 32w+32). D = bf16(relu(A @ Wp + bias)).
// ---------------------------------------------------------------------------
__device__ __forceinline__ void gemm128(const ushort* __restrict__ A,
                                        const short8* __restrict__ Wp,
                                        const float* __restrict__ bias,
                                        ushort* __restrict__ D, int tid) {
    const int l = tid & 63, w = tid >> 6;
    const int lr = l & 15, lg = l >> 4;
    const int wbase = w * 32;
    const int sw = lr & 7;
    f32x4 acc[2][8];
    const f32x4 z4 = {0.f, 0.f, 0.f, 0.f};
#pragma unroll
    for (int m = 0; m < 2; ++m)
#pragma unroll
        for (int n = 0; n < 8; ++n) acc[m][n] = z4;
#pragma unroll
    for (int kt = 0; kt < 4; ++kt) {
        const int pch = ((kt * 4 + lg) ^ sw) * 8;
        short8 a0 = *(const short8*)(A + (wbase + lr) * 128 + pch);
        short8 a1 = *(const short8*)(A + (wbase + 16 + lr) * 128 + pch);
#pragma unroll
        for (int n = 0; n < 8; ++n) {
            short8 b = Wp[(n * 4 + kt) * 64 + l];
            acc[0][n] = __builtin_amdgcn_mfma_f32_16x16x32_bf16(a0, b, acc[0][n], 0, 0, 0);
            acc[1][n] = __builtin_amdgcn_mfma_f32_16x16x32_bf16(a1, b, acc[1][n], 0, 0, 0);
        }
    }
#pragma unroll
    for (int n = 0; n < 8; ++n) {
        const int col = n * 16 + lr;
        const float bb = bias[col];
        const int cch = col >> 3, cof = col & 7;
#pragma unroll
        for (int m = 0; m < 2; ++m) {
#pragma unroll
            for (int r = 0; r < 4; ++r) {
                int row = wbase + m * 16 + lg * 4 + r;
                float t = fmaxf(acc[m][n][r] + bb, 0.f);
                D[row * 128 + ((cch ^ (row & 7)) * 8) + cof] = f2b(t);
            }
        }
    }
}

// Segmented pool of the LDS tile into pooled[g*384 + coloff + col].
__device__ __forceinline__ void pool_tile(const ushort* __restrict__ T,
                                          const int* __restrict__ batchl,
                                          float* __restrict__ pooled,
                                          int coloff, int tid) {
    int col = tid & 127, half = tid >> 7;
    int cch = col >> 3, cof = col & 7;
    float pacc = 0.f;
    int curg = -1;
    for (int r = half * 64; r < half * 64 + 64; ++r) {
        int g = batchl[r];
        if (g != curg) {
            if (curg >= 0) atomicAdd(&pooled[curg * 384 + coloff + col], pacc);
            curg = g;
            pacc = 0.f;
        }
        if (g >= 0) pacc += uf((uint)T[r * 128 + ((cch ^ (r & 7)) * 8) + cof] << 16);
    }
    if (curg >= 0) atomicAdd(&pooled[curg * 384 + coloff + col], pacc);
}

// ---------------------------------------------------------------------------
// Fused layer 1: h1 = relu(relu((x + agg(x)) @ W1 + b1) @ W2 + b2) + pool
// ---------------------------------------------------------------------------
__global__ __launch_bounds__(256) void fl1_k(const float* __restrict__ x,
                                             const int* __restrict__ batch,
                                             const int* __restrict__ row_start,
                                             const int* __restrict__ nbr,
                                             const float* __restrict__ W1, // 8x128
                                             const float* __restrict__ b1,
                                             const short8* __restrict__ Wp2,
                                             const float* __restrict__ b2,
                                             ushort* __restrict__ out,
                                             float* __restrict__ pooled, int nNodes) {
    __shared__ float hin[128][8];
    __shared__ __align__(16) ushort T[128 * 128];
    __shared__ int batchl[128];
    int t = threadIdx.x;
    int n0 = blockIdx.x * 128;
    if (t < 128) batchl[t] = (n0 + t < nNodes) ? batch[n0 + t] : -1;
    {   // gather-sum staging: 2 threads per row, unroll x8
        int r = t >> 1;
        int half = t & 1;
        int n = n0 + r;
        float4 v = make_float4(0.f, 0.f, 0.f, 0.f);
        if (n < nNodes) {
            v = *(const float4*)(x + (size_t)n * 8 + half * 4);
            int rs = row_start[n], re = row_start[n + 1];
            int p = rs;
#define AX(u) { v.x += u.x; v.y += u.y; v.z += u.z; v.w += u.w; }
            for (; p + 8 <= re; p += 8) {
                int s0 = nbr[p],     s1 = nbr[p + 1], s2 = nbr[p + 2], s3 = nbr[p + 3];
                int s4 = nbr[p + 4], s5 = nbr[p + 5], s6 = nbr[p + 6], s7 = nbr[p + 7];
                float4 u0 = *(const float4*)(x + (size_t)s0 * 8 + half * 4);
                float4 u1 = *(const float4*)(x + (size_t)s1 * 8 + half * 4);
                float4 u2 = *(const float4*)(x + (size_t)s2 * 8 + half * 4);
                float4 u3 = *(const float4*)(x + (size_t)s3 * 8 + half * 4);
                float4 u4 = *(const float4*)(x + (size_t)s4 * 8 + half * 4);
                float4 u5 = *(const float4*)(x + (size_t)s5 * 8 + half * 4);
                float4 u6 = *(const float4*)(x + (size_t)s6 * 8 + half * 4);
                float4 u7 = *(const float4*)(x + (size_t)s7 * 8 + half * 4);
                AX(u0) AX(u1) AX(u2) AX(u3) AX(u4) AX(u5) AX(u6) AX(u7)
            }
            for (; p < re; ++p) {
                int s = nbr[p];
                float4 u = *(const float4*)(x + (size_t)s * 8 + half * 4);
                AX(u)
            }
#undef AX
        }
        *(float4*)(&hin[r][half * 4]) = v;
    }
    __syncthreads();
    // MLP1 (8->128), bf16 result into swizzled T
    int tx = t & 15, ty = t >> 4;
    float w[8][8];
#pragma unroll
    for (int k = 0; k < 8; ++k) {
        float4 w0 = *(const float4*)(W1 + k * HD + tx * 8);
        float4 w1 = *(const float4*)(W1 + k * HD + tx * 8 + 4);
        w[k][0] = w0.x; w[k][1] = w0.y; w[k][2] = w0.z; w[k][3] = w0.w;
        w[k][4] = w1.x; w[k][5] = w1.y; w[k][6] = w1.z; w[k][7] = w1.w;
    }
    float4 c0 = *(const float4*)(b1 + tx * 8);
    float4 c1 = *(const float4*)(b1 + tx * 8 + 4);
    float bb[8] = {c0.x, c0.y, c0.z, c0.w, c1.x, c1.y, c1.z, c1.w};
#pragma unroll
    for (int i = 0; i < 8; ++i) {
        int r = ty * 8 + i;
        float4 a0 = *(const float4*)(&hin[r][0]);
        float4 a1 = *(const float4*)(&hin[r][4]);
        float a[8] = {a0.x, a0.y, a0.z, a0.w, a1.x, a1.y, a1.z, a1.w};
        short8 ov;
#pragma unroll
        for (int jj = 0; jj < 8; ++jj) {
            float acc = bb[jj];
#pragma unroll
            for (int k = 0; k < 8; ++k) acc += a[k] * w[k][jj];
            ov[jj] = (short)f2b(fmaxf(acc, 0.f));
        }
        *(short8*)(T + r * 128 + ((tx ^ (r & 7)) * 8)) = ov;
    }
    __syncthreads();
    gemm128(T, Wp2, b2, T, t);     // in-place, wave-private rows
    __syncthreads();
#pragma unroll
    for (int i = 0; i < 8; ++i) {
        int idx = i * 256 + t;
        int row = idx >> 4, ch = idx & 15;
        int n = n0 + row;
        if (n < nNodes) {
            short8 v = *(const short8*)(T + row * 128 + ((ch ^ (row & 7)) * 8));
            *(short8*)(out + (size_t)n * HD + ch * 8) = v;
        }
    }
    pool_tile(T, batchl, pooled, 0, t);
}

// ---------------------------------------------------------------------------
// Fused layer MLP (layers 2,3): out = relu(relu(A@W1+b1)@W2+b2) + pool.
// STORE=0 skips the global h-store (layer 3: pool is the only consumer).
// ---------------------------------------------------------------------------
template <int STORE>
__global__ __launch_bounds__(256) void fmm_k(const ushort* __restrict__ Ain,
                                             const int* __restrict__ batch,
                                             const short8* __restrict__ Wp1,
                                             const float* __restrict__ b1,
                                             const short8* __restrict__ Wp2,
                                             const float* __restrict__ b2,
                                             ushort* __restrict__ out,
                                             float* __restrict__ pooled,
                                             int coloff, int nNodes) {
    __shared__ __align__(16) ushort T[128 * 128];
    __shared__ int batchl[128];
    const int t = threadIdx.x;
    const int n0 = blockIdx.x * 128;
    if (t < 128) batchl[t] = (n0 + t < nNodes) ? batch[n0 + t] : -1;
#pragma unroll
    for (int i = 0; i < 8; ++i) {
        int idx = i * 256 + t;
        int row = idx >> 4, ch = idx & 15;
        short8 v = {0, 0, 0, 0, 0, 0, 0, 0};
        int n = n0 + row;
        if (n < nNodes) v = *(const short8*)(Ain + (size_t)n * HD + ch * 8);
        *(short8*)(T + row * 128 + ((ch ^ (row & 7)) * 8)) = v;
    }
    __syncthreads();
    gemm128(T, Wp1, b1, T, t);
    __syncthreads();
    gemm128(T, Wp2, b2, T, t);
    __syncthreads();
    if constexpr (STORE) {
#pragma unroll
        for (int i = 0; i < 8; ++i) {
            int idx = i * 256 + t;
            int row = idx >> 4, ch = idx & 15;
            int n = n0 + row;
            if (n < nNodes) {
                short8 v = *(const short8*)(T + row * 128 + ((ch ^ (row & 7)) * 8));
                *(short8*)(out + (size_t)n * HD + ch * 8) = v;
            }
        }
    }
    pool_tile(T, batchl, pooled, coloff, t);
}

// ---------------------------------------------------------------------------
// Classifier (all fp32)
// ---------------------------------------------------------------------------
__global__ __launch_bounds__(256) void cls_k(const float* __restrict__ pooled,
                                             const float* __restrict__ W1,  // 384x256
                                             const float* __restrict__ b1,
                                             const float* __restrict__ gamma,
                                             const float* __restrict__ beta,
                                             const float* __restrict__ mean,
                                             const float* __restrict__ var,
                                             const float* __restrict__ W2,  // 256x4
                                             const float* __restrict__ b2,
                                             float* __restrict__ out) {
    __shared__ float pg[384];
    __shared__ float z[256];
    int g = blockIdx.x, j = threadIdx.x;
    pg[j] = pooled[g * 384 + j];
    if (j < 128) pg[256 + j] = pooled[g * 384 + 256 + j];
    __syncthreads();
    float acc = b1[j];
    for (int k = 0; k < 384; ++k) acc += pg[k] * W1[k * 256 + j];
    acc = (acc - mean[j]) * rsqrtf(var[j] + 1e-5f) * gamma[j] + beta[j];
    z[j] = fmaxf(acc, 0.f);
    __syncthreads();
    if (j < 4) {
        float o = b2[j];
        for (int k = 0; k < 256; ++k) o += z[k] * W2[k * 4 + j];
        out[g * 4 + j] = o;
    }
}

// ---------------------------------------------------------------------------
extern "C" void kernel_launch(void* const* d_in, const int* in_sizes, int n_in,
                              void* d_out, int out_size, void* d_ws, size_t ws_size,
                              hipStream_t stream) {
    const int N = NNODES, E = NEDGES;
    const float* x     = (const float*)d_in[0];
    const int*   ei    = (const int*)d_in[1];
    const int*   batch = (const int*)d_in[2];
    const float* l1W1 = (const float*)d_in[3];
    const float* l1b1 = (const float*)d_in[4];
    const float* l1W2 = (const float*)d_in[5];
    const float* l1b2 = (const float*)d_in[6];
    const float* l2W1 = (const float*)d_in[7];
    const float* l2b1 = (const float*)d_in[8];
    const float* l2W2 = (const float*)d_in[9];
    const float* l2b2 = (const float*)d_in[10];
    const float* l3W1 = (const float*)d_in[11];
    const float* l3b1 = (const float*)d_in[12];
    const float* l3W2 = (const float*)d_in[13];
    const float* l3b2 = (const float*)d_in[14];
    const float* cW1  = (const float*)d_in[15];
    const float* cb1  = (const float*)d_in[16];
    const float* bnG  = (const float*)d_in[17];
    const float* bnB  = (const float*)d_in[18];
    const float* bnM  = (const float*)d_in[19];
    const float* bnV  = (const float*)d_in[20];
    const float* cW2  = (const float*)d_in[21];
    const float* cb2  = (const float*)d_in[22];

    const int* src = ei;
    const int* dst = ei + E;

    // ---- workspace layout ----
    char* wsp = (char*)d_ws;
    ushort* tmpb = (ushort*)wsp;  wsp += (size_t)N * HD * 2;
    ushort* h1   = (ushort*)wsp;  wsp += (size_t)N * HD * 2;
    ushort* h2   = (ushort*)wsp;  wsp += (size_t)N * HD * 2;
    float* pooled = (float*)wsp;  wsp += (size_t)64 * 384 * 4;
    ushort* wp    = (ushort*)wsp; wsp += (size_t)5 * 16384 * 2;
    int* count    = (int*)wsp;    wsp += (size_t)N * 4;
    int* row_start = (int*)wsp;   wsp += (size_t)(N + 1) * 4;
    int* cur       = (int*)wsp;   wsp += (size_t)N * 4;
    int* nbr       = (int*)wsp;   wsp += (size_t)E * 4;

    // setup: weight pack + zero count/pooled, then CSR build
    wpinit_k<<<dim3(8, 5), 256, 0, stream>>>(l1W2, l2W1, l2W2, l3W1, l3W2,
                                             wp, count, pooled);
    hist_k<<<(E + 255) / 256, 256, 0, stream>>>(dst, count, E);
    scan_k<<<1, 1024, 0, stream>>>(count, row_start, cur, N, E);
    scatter_k<<<(E + 255) / 256, 256, 0, stream>>>(src, dst, cur, nbr, E);

    const short8* Wp0 = (const short8*)(wp);
    const short8* Wp1 = (const short8*)(wp + 16384);
    const short8* Wp2 = (const short8*)(wp + 2 * 16384);
    const short8* Wp3 = (const short8*)(wp + 3 * 16384);
    const short8* Wp4 = (const short8*)(wp + 4 * 16384);

    const int mb = (N + 127) / 128;              // 391 tiles
    const int ab = ((N + 1) / 2 * 64) / 256;     // 6250 blocks
    // layer 1 (gather + MLP1 + GEMM2 + pool fused)
    fl1_k<<<mb, 256, 0, stream>>>(x, batch, row_start, nbr, l1W1, l1b1, Wp0, l1b2,
                                  h1, pooled, N);
    // layer 2
    aggb_k<<<ab, 256, 0, stream>>>(h1, row_start, nbr, tmpb, N);
    fmm_k<1><<<mb, 256, 0, stream>>>(tmpb, batch, Wp1, l2b1, Wp2, l2b2, h2,
                                     pooled, 128, N);
    // layer 3 (no h3 store: pool is the only consumer)
    aggb_k<<<ab, 256, 0, stream>>>(h2, row_start, nbr, tmpb, N);
    fmm_k<0><<<mb, 256, 0, stream>>>(tmpb, batch, Wp3, l3b1, Wp4, l3b2, nullptr,
                                     pooled, 256, N);
    // classifier
    cls_k<<<NGRAPH, 256, 0, stream>>>(pooled, cW1, cb1, bnG, bnB, bnM, bnV, cW2, cb2,
                                      (float*)d_out);
}

// Round 7
// 221.451 us; speedup vs baseline: 1.5334x; 1.5301x over previous
//
#include <hip/hip_runtime.h>
#include <hip/hip_bf16.h>

#define NNODES 50000
#define NEDGES 640000
#define NGRAPH 64
#define HD     128

typedef __attribute__((ext_vector_type(8))) short short8;
typedef __attribute__((ext_vector_type(4))) float f32x4;

__device__ __forceinline__ float uf(uint u) { return __uint_as_float(u); }
// fp32 -> bf16 round-to-nearest-even
__device__ __forceinline__ ushort f2b(float f) {
    uint u = __float_as_uint(f);
    return (ushort)((u + 0x7fffu + ((u >> 16) & 1u)) >> 16);
}

// ---------------------------------------------------------------------------
// wpinit: pack 5 fp32 128x128 weights into bf16 MFMA B-fragment order,
// AND zero count[] + pooled[] (grid-stride over the dim3(8,5) x 256 grid).
// ---------------------------------------------------------------------------
__global__ __launch_bounds__(256) void wpinit_k(const float* __restrict__ W0,
                                                const float* __restrict__ W1,
                                                const float* __restrict__ W2,
                                                const float* __restrict__ W3,
                                                const float* __restrict__ W4,
                                                ushort* __restrict__ Wp,
                                                int* __restrict__ count,
                                                float* __restrict__ pooled) {
    int which = blockIdx.y;
    const float* W = (which == 0) ? W0 : (which == 1) ? W1 : (which == 2) ? W2
                   : (which == 3) ? W3 : W4;
    ushort* dst = Wp + (size_t)which * 16384;
    int idx = blockIdx.x * 256 + threadIdx.x;   // 0..2047
    int l  = idx & 63;
    int kt = (idx >> 6) & 3;
    int nt = idx >> 8;
    int krow = kt * 32 + (l >> 4) * 8;
    int col  = nt * 16 + (l & 15);
    short8 v;
#pragma unroll
    for (int j = 0; j < 8; ++j) v[j] = (short)f2b(W[(size_t)(krow + j) * HD + col]);
    *(short8*)(dst + ((size_t)(nt * 4 + kt) * 64 + l) * 8) = v;
    // zeroing: flat id over 10240 threads
    int fid = (blockIdx.y * 8 + blockIdx.x) * 256 + threadIdx.x;
    for (int i = fid; i < NNODES; i += 10240) count[i] = 0;
    for (int i = fid; i < NGRAPH * 384; i += 10240) pooled[i] = 0.f;
}

// ---------------------------------------------------------------------------
// CSR build: histogram -> block scan -> (re-scan blocksums + finalize) -> scatter
// ---------------------------------------------------------------------------
__global__ __launch_bounds__(256) void hist_k(const int* __restrict__ dst,
                                              int* __restrict__ count, int E) {
    int e = blockIdx.x * 256 + threadIdx.x;
    if (e < E) atomicAdd(&count[dst[e]], 1);
}

__global__ __launch_bounds__(256) void scan1_k(const int* __restrict__ count,
                                               int* __restrict__ row_tmp,
                                               int* __restrict__ blocksum, int N) {
    __shared__ int s[256];
    int t = threadIdx.x;
    int i = blockIdx.x * 256 + t;
    int v = (i < N) ? count[i] : 0;
    s[t] = v;
    __syncthreads();
    for (int off = 1; off < 256; off <<= 1) {
        int nv = s[t];
        if (t >= off) nv += s[t - off];
        __syncthreads();
        s[t] = nv;
        __syncthreads();
    }
    if (i < N) row_tmp[i] = s[t];          // inclusive within block
    if (t == 255) blocksum[blockIdx.x] = s[255];
}

// every block re-scans the (<=256) blocksums locally, then finalizes its rows
__global__ __launch_bounds__(256) void scan23_k(const int* __restrict__ count,
                                                const int* __restrict__ row_tmp,
                                                const int* __restrict__ blocksum,
                                                int nB,
                                                int* __restrict__ row_start,
                                                int* __restrict__ cur, int N, int E) {
    __shared__ int s[256];
    int t = threadIdx.x;
    s[t] = (t < nB) ? blocksum[t] : 0;
    __syncthreads();
    for (int off = 1; off < 256; off <<= 1) {
        int nv = s[t];
        if (t >= off) nv += s[t - off];
        __syncthreads();
        s[t] = nv;
        __syncthreads();
    }
    int bid = blockIdx.x;
    int boff = (bid == 0) ? 0 : s[bid - 1];
    int i = bid * 256 + t;
    if (i < N) {
        int excl = row_tmp[i] - count[i] + boff;
        row_start[i] = excl;
        cur[i] = excl;
    }
    if (i == N) row_start[N] = E;
}

__global__ __launch_bounds__(256) void scatter_k(const int* __restrict__ src,
                                                 const int* __restrict__ dst,
                                                 int* __restrict__ cur,
                                                 int* __restrict__ nbr, int E) {
    int e = blockIdx.x * 256 + threadIdx.x;
    if (e < E) {
        int d = dst[e];
        int pos = atomicAdd(&cur[d], 1);
        nbr[pos] = src[e];
    }
}

// ---------------------------------------------------------------------------
// bf16 aggregation: out[n] = h[n] + sum_{s in nbr(n)} h[s]   (fp32 accumulate)
// 2 nodes per wave; neighbor walk unrolled x8 (16 rows in flight/wave).
// ---------------------------------------------------------------------------
__global__ __launch_bounds__(256) void aggb_k(const ushort* __restrict__ h,
                                              const int* __restrict__ row_start,
                                              const int* __restrict__ nbr,
                                              ushort* __restrict__ out, int nNodes) {
    int gw   = (blockIdx.x * 256 + threadIdx.x) >> 6;
    int lane = threadIdx.x & 63;
    int node = gw * 2 + (lane >> 5);
    int sub  = lane & 31;
    if (node >= nNodes) return;
    const uint2* hp = (const uint2*)h;
    uint2 u = hp[(size_t)node * 32 + sub];
    float f0 = uf(u.x << 16), f1 = uf(u.x & 0xffff0000u);
    float f2v = uf(u.y << 16), f3 = uf(u.y & 0xffff0000u);
    int rs = row_start[node], re = row_start[node + 1];
    int p = rs;
#define ACC4(vv) { f0 += uf(vv.x << 16); f1 += uf(vv.x & 0xffff0000u); \
                   f2v += uf(vv.y << 16); f3 += uf(vv.y & 0xffff0000u); }
    for (; p + 8 <= re; p += 8) {
        int s0 = nbr[p],     s1 = nbr[p + 1], s2 = nbr[p + 2], s3 = nbr[p + 3];
        int s4 = nbr[p + 4], s5 = nbr[p + 5], s6 = nbr[p + 6], s7 = nbr[p + 7];
        uint2 v0 = hp[(size_t)s0 * 32 + sub];
        uint2 v1 = hp[(size_t)s1 * 32 + sub];
        uint2 v2 = hp[(size_t)s2 * 32 + sub];
        uint2 v3 = hp[(size_t)s3 * 32 + sub];
        uint2 v4 = hp[(size_t)s4 * 32 + sub];
        uint2 v5 = hp[(size_t)s5 * 32 + sub];
        uint2 v6 = hp[(size_t)s6 * 32 + sub];
        uint2 v7 = hp[(size_t)s7 * 32 + sub];
        ACC4(v0) ACC4(v1) ACC4(v2) ACC4(v3)
        ACC4(v4) ACC4(v5) ACC4(v6) ACC4(v7)
    }
    for (; p + 4 <= re; p += 4) {
        int s0 = nbr[p], s1 = nbr[p + 1], s2 = nbr[p + 2], s3 = nbr[p + 3];
        uint2 v0 = hp[(size_t)s0 * 32 + sub];
        uint2 v1 = hp[(size_t)s1 * 32 + sub];
        uint2 v2 = hp[(size_t)s2 * 32 + sub];
        uint2 v3 = hp[(size_t)s3 * 32 + sub];
        ACC4(v0) ACC4(v1) ACC4(v2) ACC4(v3)
    }
    for (; p < re; ++p) {
        int s = nbr[p];
        uint2 v = hp[(size_t)s * 32 + sub];
        ACC4(v)
    }
#undef ACC4
    uint2 o;
    o.x = (uint)f2b(f0) | ((uint)f2b(f1) << 16);
    o.y = (uint)f2b(f2v) | ((uint)f2b(f3) << 16);
    ((uint2*)out)[(size_t)node * 32 + sub] = o;
}

// ---------------------------------------------------------------------------
// 128x128 bf16 MFMA GEMM step on an LDS tile. In-place safe: wave w only
// reads/writes rows [32w, 32w+32). D = bf16(relu(A @ Wp + bias)).
// ---------------------------------------------------------------------------
__device__ __forceinline__ void gemm128(const ushort* __restrict__ A,
                                        const short8* __restrict__ Wp,
                                        const float* __restrict__ bias,
                                        ushort* __restrict__ D, int tid) {
    const int l = tid & 63, w = tid >> 6;
    const int lr = l & 15, lg = l >> 4;
    const int wbase = w * 32;
    const int sw = lr & 7;
    f32x4 acc[2][8];
    const f32x4 z4 = {0.f, 0.f, 0.f, 0.f};
#pragma unroll
    for (int m = 0; m < 2; ++m)
#pragma unroll
        for (int n = 0; n < 8; ++n) acc[m][n] = z4;
#pragma unroll
    for (int kt = 0; kt < 4; ++kt) {
        const int pch = ((kt * 4 + lg) ^ sw) * 8;
        short8 a0 = *(const short8*)(A + (wbase + lr) * 128 + pch);
        short8 a1 = *(const short8*)(A + (wbase + 16 + lr) * 128 + pch);
#pragma unroll
        for (int n = 0; n < 8; ++n) {
            short8 b = Wp[(n * 4 + kt) * 64 + l];
            acc[0][n] = __builtin_amdgcn_mfma_f32_16x16x32_bf16(a0, b, acc[0][n], 0, 0, 0);
            acc[1][n] = __builtin_amdgcn_mfma_f32_16x16x32_bf16(a1, b, acc[1][n], 0, 0, 0);
        }
    }
#pragma unroll
    for (int n = 0; n < 8; ++n) {
        const int col = n * 16 + lr;
        const float bb = bias[col];
        const int cch = col >> 3, cof = col & 7;
#pragma unroll
        for (int m = 0; m < 2; ++m) {
#pragma unroll
            for (int r = 0; r < 4; ++r) {
                int row = wbase + m * 16 + lg * 4 + r;
                float t = fmaxf(acc[m][n][r] + bb, 0.f);
                D[row * 128 + ((cch ^ (row & 7)) * 8) + cof] = f2b(t);
            }
        }
    }
}

// Segmented pool of the LDS tile into pooled[g*384 + coloff + col].
__device__ __forceinline__ void pool_tile(const ushort* __restrict__ T,
                                          const int* __restrict__ batchl,
                                          float* __restrict__ pooled,
                                          int coloff, int tid) {
    int col = tid & 127, half = tid >> 7;
    int cch = col >> 3, cof = col & 7;
    float pacc = 0.f;
    int curg = -1;
    for (int r = half * 64; r < half * 64 + 64; ++r) {
        int g = batchl[r];
        if (g != curg) {
            if (curg >= 0) atomicAdd(&pooled[curg * 384 + coloff + col], pacc);
            curg = g;
            pacc = 0.f;
        }
        if (g >= 0) pacc += uf((uint)T[r * 128 + ((cch ^ (r & 7)) * 8) + cof] << 16);
    }
    if (curg >= 0) atomicAdd(&pooled[curg * 384 + coloff + col], pacc);
}

// ---------------------------------------------------------------------------
// Fused layer 1: h1 = relu(relu((x + agg(x)) @ W1 + b1) @ W2 + b2) + pool
// ---------------------------------------------------------------------------
__global__ __launch_bounds__(256) void fl1_k(const float* __restrict__ x,
                                             const int* __restrict__ batch,
                                             const int* __restrict__ row_start,
                                             const int* __restrict__ nbr,
                                             const float* __restrict__ W1, // 8x128
                                             const float* __restrict__ b1,
                                             const short8* __restrict__ Wp2,
                                             const float* __restrict__ b2,
                                             ushort* __restrict__ out,
                                             float* __restrict__ pooled, int nNodes) {
    __shared__ float hin[128][8];
    __shared__ __align__(16) ushort T[128 * 128];
    __shared__ int batchl[128];
    int t = threadIdx.x;
    int n0 = blockIdx.x * 128;
    if (t < 128) batchl[t] = (n0 + t < nNodes) ? batch[n0 + t] : -1;
    {   // gather-sum staging: 2 threads per row, unroll x8
        int r = t >> 1;
        int half = t & 1;
        int n = n0 + r;
        float4 v = make_float4(0.f, 0.f, 0.f, 0.f);
        if (n < nNodes) {
            v = *(const float4*)(x + (size_t)n * 8 + half * 4);
            int rs = row_start[n], re = row_start[n + 1];
            int p = rs;
#define AX(u) { v.x += u.x; v.y += u.y; v.z += u.z; v.w += u.w; }
            for (; p + 8 <= re; p += 8) {
                int s0 = nbr[p],     s1 = nbr[p + 1], s2 = nbr[p + 2], s3 = nbr[p + 3];
                int s4 = nbr[p + 4], s5 = nbr[p + 5], s6 = nbr[p + 6], s7 = nbr[p + 7];
                float4 u0 = *(const float4*)(x + (size_t)s0 * 8 + half * 4);
                float4 u1 = *(const float4*)(x + (size_t)s1 * 8 + half * 4);
                float4 u2 = *(const float4*)(x + (size_t)s2 * 8 + half * 4);
                float4 u3 = *(const float4*)(x + (size_t)s3 * 8 + half * 4);
                float4 u4 = *(const float4*)(x + (size_t)s4 * 8 + half * 4);
                float4 u5 = *(const float4*)(x + (size_t)s5 * 8 + half * 4);
                float4 u6 = *(const float4*)(x + (size_t)s6 * 8 + half * 4);
                float4 u7 = *(const float4*)(x + (size_t)s7 * 8 + half * 4);
                AX(u0) AX(u1) AX(u2) AX(u3) AX(u4) AX(u5) AX(u6) AX(u7)
            }
            for (; p < re; ++p) {
                int s = nbr[p];
                float4 u = *(const float4*)(x + (size_t)s * 8 + half * 4);
                AX(u)
            }
#undef AX
        }
        *(float4*)(&hin[r][half * 4]) = v;
    }
    __syncthreads();
    // MLP1 (8->128), bf16 result into swizzled T
    int tx = t & 15, ty = t >> 4;
    float w[8][8];
#pragma unroll
    for (int k = 0; k < 8; ++k) {
        float4 w0 = *(const float4*)(W1 + k * HD + tx * 8);
        float4 w1 = *(const float4*)(W1 + k * HD + tx * 8 + 4);
        w[k][0] = w0.x; w[k][1] = w0.y; w[k][2] = w0.z; w[k][3] = w0.w;
        w[k][4] = w1.x; w[k][5] = w1.y; w[k][6] = w1.z; w[k][7] = w1.w;
    }
    float4 c0 = *(const float4*)(b1 + tx * 8);
    float4 c1 = *(const float4*)(b1 + tx * 8 + 4);
    float bb[8] = {c0.x, c0.y, c0.z, c0.w, c1.x, c1.y, c1.z, c1.w};
#pragma unroll
    for (int i = 0; i < 8; ++i) {
        int r = ty * 8 + i;
        float4 a0 = *(const float4*)(&hin[r][0]);
        float4 a1 = *(const float4*)(&hin[r][4]);
        float a[8] = {a0.x, a0.y, a0.z, a0.w, a1.x, a1.y, a1.z, a1.w};
        short8 ov;
#pragma unroll
        for (int jj = 0; jj < 8; ++jj) {
            float acc = bb[jj];
#pragma unroll
            for (int k = 0; k < 8; ++k) acc += a[k] * w[k][jj];
            ov[jj] = (short)f2b(fmaxf(acc, 0.f));
        }
        *(short8*)(T + r * 128 + ((tx ^ (r & 7)) * 8)) = ov;
    }
    __syncthreads();
    gemm128(T, Wp2, b2, T, t);     // in-place, wave-private rows
    __syncthreads();
#pragma unroll
    for (int i = 0; i < 8; ++i) {
        int idx = i * 256 + t;
        int row = idx >> 4, ch = idx & 15;
        int n = n0 + row;
        if (n < nNodes) {
            short8 v = *(const short8*)(T + row * 128 + ((ch ^ (row & 7)) * 8));
            *(short8*)(out + (size_t)n * HD + ch * 8) = v;
        }
    }
    pool_tile(T, batchl, pooled, 0, t);
}

// ---------------------------------------------------------------------------
// Fused layer MLP (layers 2,3): out = relu(relu(A@W1+b1)@W2+b2) + pool.
// STORE=0 skips the global h-store (layer 3: pool is the only consumer).
// ---------------------------------------------------------------------------
template <int STORE>
__global__ __launch_bounds__(256) void fmm_k(const ushort* __restrict__ Ain,
                                             const int* __restrict__ batch,
                                             const short8* __restrict__ Wp1,
                                             const float* __restrict__ b1,
                                             const short8* __restrict__ Wp2,
                                             const float* __restrict__ b2,
                                             ushort* __restrict__ out,
                                             float* __restrict__ pooled,
                                             int coloff, int nNodes) {
    __shared__ __align__(16) ushort T[128 * 128];
    __shared__ int batchl[128];
    const int t = threadIdx.x;
    const int n0 = blockIdx.x * 128;
    if (t < 128) batchl[t] = (n0 + t < nNodes) ? batch[n0 + t] : -1;
#pragma unroll
    for (int i = 0; i < 8; ++i) {
        int idx = i * 256 + t;
        int row = idx >> 4, ch = idx & 15;
        short8 v = {0, 0, 0, 0, 0, 0, 0, 0};
        int n = n0 + row;
        if (n < nNodes) v = *(const short8*)(Ain + (size_t)n * HD + ch * 8);
        *(short8*)(T + row * 128 + ((ch ^ (row & 7)) * 8)) = v;
    }
    __syncthreads();
    gemm128(T, Wp1, b1, T, t);
    __syncthreads();
    gemm128(T, Wp2, b2, T, t);
    __syncthreads();
    if constexpr (STORE) {
#pragma unroll
        for (int i = 0; i < 8; ++i) {
            int idx = i * 256 + t;
            int row = idx >> 4, ch = idx & 15;
            int n = n0 + row;
            if (n < nNodes) {
                short8 v = *(const short8*)(T + row * 128 + ((ch ^ (row & 7)) * 8));
                *(short8*)(out + (size_t)n * HD + ch * 8) = v;
            }
        }
    }
    pool_tile(T, batchl, pooled, coloff, t);
}

// ---------------------------------------------------------------------------
// Classifier (all fp32)
// ---------------------------------------------------------------------------
__global__ __launch_bounds__(256) void cls_k(const float* __restrict__ pooled,
                                             const float* __restrict__ W1,  // 384x256
                                             const float* __restrict__ b1,
                                             const float* __restrict__ gamma,
                                             const float* __restrict__ beta,
                                             const float* __restrict__ mean,
                                             const float* __restrict__ var,
                                             const float* __restrict__ W2,  // 256x4
                                             const float* __restrict__ b2,
                                             float* __restrict__ out) {
    __shared__ float pg[384];
    __shared__ float z[256];
    int g = blockIdx.x, j = threadIdx.x;
    pg[j] = pooled[g * 384 + j];
    if (j < 128) pg[256 + j] = pooled[g * 384 + 256 + j];
    __syncthreads();
    float acc = b1[j];
    for (int k = 0; k < 384; ++k) acc += pg[k] * W1[k * 256 + j];
    acc = (acc - mean[j]) * rsqrtf(var[j] + 1e-5f) * gamma[j] + beta[j];
    z[j] = fmaxf(acc, 0.f);
    __syncthreads();
    if (j < 4) {
        float o = b2[j];
        for (int k = 0; k < 256; ++k) o += z[k] * W2[k * 4 + j];
        out[g * 4 + j] = o;
    }
}

// ---------------------------------------------------------------------------
extern "C" void kernel_launch(void* const* d_in, const int* in_sizes, int n_in,
                              void* d_out, int out_size, void* d_ws, size_t ws_size,
                              hipStream_t stream) {
    const int N = NNODES, E = NEDGES;
    const float* x     = (const float*)d_in[0];
    const int*   ei    = (const int*)d_in[1];
    const int*   batch = (const int*)d_in[2];
    const float* l1W1 = (const float*)d_in[3];
    const float* l1b1 = (const float*)d_in[4];
    const float* l1W2 = (const float*)d_in[5];
    const float* l1b2 = (const float*)d_in[6];
    const float* l2W1 = (const float*)d_in[7];
    const float* l2b1 = (const float*)d_in[8];
    const float* l2W2 = (const float*)d_in[9];
    const float* l2b2 = (const float*)d_in[10];
    const float* l3W1 = (const float*)d_in[11];
    const float* l3b1 = (const float*)d_in[12];
    const float* l3W2 = (const float*)d_in[13];
    const float* l3b2 = (const float*)d_in[14];
    const float* cW1  = (const float*)d_in[15];
    const float* cb1  = (const float*)d_in[16];
    const float* bnG  = (const float*)d_in[17];
    const float* bnB  = (const float*)d_in[18];
    const float* bnM  = (const float*)d_in[19];
    const float* bnV  = (const float*)d_in[20];
    const float* cW2  = (const float*)d_in[21];
    const float* cb2  = (const float*)d_in[22];

    const int* src = ei;
    const int* dst = ei + E;

    // ---- workspace layout ----
    char* wsp = (char*)d_ws;
    ushort* tmpb = (ushort*)wsp;  wsp += (size_t)N * HD * 2;
    ushort* h1   = (ushort*)wsp;  wsp += (size_t)N * HD * 2;
    ushort* h2   = (ushort*)wsp;  wsp += (size_t)N * HD * 2;
    float* pooled = (float*)wsp;  wsp += (size_t)64 * 384 * 4;
    ushort* wp    = (ushort*)wsp; wsp += (size_t)5 * 16384 * 2;
    int* count    = (int*)wsp;    wsp += (size_t)N * 4;
    int* row_tmp  = (int*)wsp;    wsp += (size_t)N * 4;
    int* blocksum = (int*)wsp;    wsp += 256 * 4;
    int* row_start = (int*)wsp;   wsp += (size_t)(N + 1) * 4;
    int* cur       = (int*)wsp;   wsp += (size_t)N * 4;
    int* nbr       = (int*)wsp;   wsp += (size_t)E * 4;

    const int nB = (N + 255) / 256;              // 196
    // setup: weight pack + zero count/pooled, then CSR build (parallel scan)
    wpinit_k<<<dim3(8, 5), 256, 0, stream>>>(l1W2, l2W1, l2W2, l3W1, l3W2,
                                             wp, count, pooled);
    hist_k<<<(E + 255) / 256, 256, 0, stream>>>(dst, count, E);
    scan1_k<<<nB, 256, 0, stream>>>(count, row_tmp, blocksum, N);
    scan23_k<<<nB, 256, 0, stream>>>(count, row_tmp, blocksum, nB, row_start, cur, N, E);
    scatter_k<<<(E + 255) / 256, 256, 0, stream>>>(src, dst, cur, nbr, E);

    const short8* Wp0 = (const short8*)(wp);
    const short8* Wp1 = (const short8*)(wp + 16384);
    const short8* Wp2 = (const short8*)(wp + 2 * 16384);
    const short8* Wp3 = (const short8*)(wp + 3 * 16384);
    const short8* Wp4 = (const short8*)(wp + 4 * 16384);

    const int mb = (N + 127) / 128;              // 391 tiles
    const int ab = ((N + 1) / 2 * 64) / 256;     // 6250 blocks
    // layer 1 (gather + MLP1 + GEMM2 + pool fused)
    fl1_k<<<mb, 256, 0, stream>>>(x, batch, row_start, nbr, l1W1, l1b1, Wp0, l1b2,
                                  h1, pooled, N);
    // layer 2
    aggb_k<<<ab, 256, 0, stream>>>(h1, row_start, nbr, tmpb, N);
    fmm_k<1><<<mb, 256, 0, stream>>>(tmpb, batch, Wp1, l2b1, Wp2, l2b2, h2,
                                     pooled, 128, N);
    // layer 3 (no h3 store: pool is the only consumer)
    aggb_k<<<ab, 256, 0, stream>>>(h2, row_start, nbr, tmpb, N);
    fmm_k<0><<<mb, 256, 0, stream>>>(tmpb, batch, Wp3, l3b1, Wp4, l3b2, nullptr,
                                     pooled, 256, N);
    // classifier
    cls_k<<<NGRAPH, 256, 0, stream>>>(pooled, cW1, cb1, bnG, bnB, bnM, bnV, cW2, cb2,
                                      (float*)d_out);
}

// Round 8
// 215.216 us; speedup vs baseline: 1.5778x; 1.0290x over previous
//
#include <hip/hip_runtime.h>
#include <hip/hip_bf16.h>

#define NNODES 50000
#define NEDGES 640000
#define NGRAPH 64
#define HD     128
#define NPART  8
#define PRANGE (NNODES / NPART)   // 6250

typedef __attribute__((ext_vector_type(8))) short short8;
typedef __attribute__((ext_vector_type(4))) float f32x4;

__device__ __forceinline__ float uf(uint u) { return __uint_as_float(u); }
// fp32 -> bf16 round-to-nearest-even
__device__ __forceinline__ ushort f2b(float f) {
    uint u = __float_as_uint(f);
    return (ushort)((u + 0x7fffu + ((u >> 16) & 1u)) >> 16);
}

// ---------------------------------------------------------------------------
// wpinit: pack 5 fp32 128x128 weights into bf16 MFMA B-fragment order,
// AND zero count[] + pooled[] (grid-stride over the dim3(8,5) x 256 grid).
// ---------------------------------------------------------------------------
__global__ __launch_bounds__(256) void wpinit_k(const float* __restrict__ W0,
                                                const float* __restrict__ W1,
                                                const float* __restrict__ W2,
                                                const float* __restrict__ W3,
                                                const float* __restrict__ W4,
                                                ushort* __restrict__ Wp,
                                                int* __restrict__ count,
                                                float* __restrict__ pooled) {
    int which = blockIdx.y;
    const float* W = (which == 0) ? W0 : (which == 1) ? W1 : (which == 2) ? W2
                   : (which == 3) ? W3 : W4;
    ushort* dst = Wp + (size_t)which * 16384;
    int idx = blockIdx.x * 256 + threadIdx.x;   // 0..2047
    int l  = idx & 63;
    int kt = (idx >> 6) & 3;
    int nt = idx >> 8;
    int krow = kt * 32 + (l >> 4) * 8;
    int col  = nt * 16 + (l & 15);
    short8 v;
#pragma unroll
    for (int j = 0; j < 8; ++j) v[j] = (short)f2b(W[(size_t)(krow + j) * HD + col]);
    *(short8*)(dst + ((size_t)(nt * 4 + kt) * 64 + l) * 8) = v;
    // zeroing: flat id over 10240 threads
    int fid = (blockIdx.y * 8 + blockIdx.x) * 256 + threadIdx.x;
    for (int i = fid; i < NNODES; i += 10240) count[i] = 0;
    for (int i = fid; i < NGRAPH * 384; i += 10240) pooled[i] = 0.f;
}

// ---------------------------------------------------------------------------
// CSR build, XCD-partitioned: blocks with blockIdx%8==p own dst range
// [p*PRANGE, (p+1)*PRANGE) -> atomics and scattered writes stay in one XCD's
// L2 instead of bouncing lines across all 8 (round-7 scatter: 38 MB writeback).
// ---------------------------------------------------------------------------
__global__ __launch_bounds__(256) void phist_k(const int* __restrict__ dst,
                                               int* __restrict__ count, int E) {
    int p = blockIdx.x & 7;
    int q = blockIdx.x >> 3;                  // 0..255
    int lo = p * PRANGE, hi = lo + PRANGE;
    for (int e = q * 256 + threadIdx.x; e < E; e += 256 * 256) {
        int d = dst[e];
        if (d >= lo && d < hi) atomicAdd(&count[d], 1);
    }
}

__global__ __launch_bounds__(256) void scan1_k(const int* __restrict__ count,
                                               int* __restrict__ row_tmp,
                                               int* __restrict__ blocksum, int N) {
    __shared__ int s[256];
    int t = threadIdx.x;
    int i = blockIdx.x * 256 + t;
    int v = (i < N) ? count[i] : 0;
    s[t] = v;
    __syncthreads();
    for (int off = 1; off < 256; off <<= 1) {
        int nv = s[t];
        if (t >= off) nv += s[t - off];
        __syncthreads();
        s[t] = nv;
        __syncthreads();
    }
    if (i < N) row_tmp[i] = s[t];          // inclusive within block
    if (t == 255) blocksum[blockIdx.x] = s[255];
}

// every block re-scans the (<=256) blocksums locally, then finalizes its rows
__global__ __launch_bounds__(256) void scan23_k(const int* __restrict__ count,
                                                const int* __restrict__ row_tmp,
                                                const int* __restrict__ blocksum,
                                                int nB,
                                                int* __restrict__ row_start,
                                                int* __restrict__ cur, int N, int E) {
    __shared__ int s[256];
    int t = threadIdx.x;
    s[t] = (t < nB) ? blocksum[t] : 0;
    __syncthreads();
    for (int off = 1; off < 256; off <<= 1) {
        int nv = s[t];
        if (t >= off) nv += s[t - off];
        __syncthreads();
        s[t] = nv;
        __syncthreads();
    }
    int bid = blockIdx.x;
    int boff = (bid == 0) ? 0 : s[bid - 1];
    int i = bid * 256 + t;
    if (i < N) {
        int excl = row_tmp[i] - count[i] + boff;
        row_start[i] = excl;
        cur[i] = excl;
    }
    if (i == N) row_start[N] = E;
}

__global__ __launch_bounds__(256) void pscatter_k(const int* __restrict__ src,
                                                  const int* __restrict__ dst,
                                                  int* __restrict__ cur,
                                                  ushort* __restrict__ nbr, int E) {
    int p = blockIdx.x & 7;
    int q = blockIdx.x >> 3;
    int lo = p * PRANGE, hi = lo + PRANGE;
    for (int e = q * 256 + threadIdx.x; e < E; e += 256 * 256) {
        int d = dst[e];
        if (d >= lo && d < hi) {
            int pos = atomicAdd(&cur[d], 1);
            nbr[pos] = (ushort)src[e];
        }
    }
}

// ---------------------------------------------------------------------------
// bf16 aggregation: out[n] = h[n] + sum_{s in nbr(n)} h[s]   (fp32 accumulate)
// 2 nodes per wave; neighbor walk unrolled x8 (16 rows in flight/wave).
// ---------------------------------------------------------------------------
__global__ __launch_bounds__(256) void aggb_k(const ushort* __restrict__ h,
                                              const int* __restrict__ row_start,
                                              const ushort* __restrict__ nbr,
                                              ushort* __restrict__ out, int nNodes) {
    int gw   = (blockIdx.x * 256 + threadIdx.x) >> 6;
    int lane = threadIdx.x & 63;
    int node = gw * 2 + (lane >> 5);
    int sub  = lane & 31;
    if (node >= nNodes) return;
    const uint2* hp = (const uint2*)h;
    uint2 u = hp[(size_t)node * 32 + sub];
    float f0 = uf(u.x << 16), f1 = uf(u.x & 0xffff0000u);
    float f2v = uf(u.y << 16), f3 = uf(u.y & 0xffff0000u);
    int rs = row_start[node], re = row_start[node + 1];
    int p = rs;
#define ACC4(vv) { f0 += uf(vv.x << 16); f1 += uf(vv.x & 0xffff0000u); \
                   f2v += uf(vv.y << 16); f3 += uf(vv.y & 0xffff0000u); }
    for (; p + 8 <= re; p += 8) {
        int s0 = nbr[p],     s1 = nbr[p + 1], s2 = nbr[p + 2], s3 = nbr[p + 3];
        int s4 = nbr[p + 4], s5 = nbr[p + 5], s6 = nbr[p + 6], s7 = nbr[p + 7];
        uint2 v0 = hp[(size_t)s0 * 32 + sub];
        uint2 v1 = hp[(size_t)s1 * 32 + sub];
        uint2 v2 = hp[(size_t)s2 * 32 + sub];
        uint2 v3 = hp[(size_t)s3 * 32 + sub];
        uint2 v4 = hp[(size_t)s4 * 32 + sub];
        uint2 v5 = hp[(size_t)s5 * 32 + sub];
        uint2 v6 = hp[(size_t)s6 * 32 + sub];
        uint2 v7 = hp[(size_t)s7 * 32 + sub];
        ACC4(v0) ACC4(v1) ACC4(v2) ACC4(v3)
        ACC4(v4) ACC4(v5) ACC4(v6) ACC4(v7)
    }
    for (; p + 4 <= re; p += 4) {
        int s0 = nbr[p], s1 = nbr[p + 1], s2 = nbr[p + 2], s3 = nbr[p + 3];
        uint2 v0 = hp[(size_t)s0 * 32 + sub];
        uint2 v1 = hp[(size_t)s1 * 32 + sub];
        uint2 v2 = hp[(size_t)s2 * 32 + sub];
        uint2 v3 = hp[(size_t)s3 * 32 + sub];
        ACC4(v0) ACC4(v1) ACC4(v2) ACC4(v3)
    }
    for (; p < re; ++p) {
        int s = nbr[p];
        uint2 v = hp[(size_t)s * 32 + sub];
        ACC4(v)
    }
#undef ACC4
    uint2 o;
    o.x = (uint)f2b(f0) | ((uint)f2b(f1) << 16);
    o.y = (uint)f2b(f2v) | ((uint)f2b(f3) << 16);
    ((uint2*)out)[(size_t)node * 32 + sub] = o;
}

// ---------------------------------------------------------------------------
// 128x128 bf16 MFMA GEMM step on an LDS tile. In-place safe: wave w only
// reads/writes rows [32w, 32w+32). D = bf16(relu(A @ Wp + bias)).
// ---------------------------------------------------------------------------
__device__ __forceinline__ void gemm128(const ushort* __restrict__ A,
                                        const short8* __restrict__ Wp,
                                        const float* __restrict__ bias,
                                        ushort* __restrict__ D, int tid) {
    const int l = tid & 63, w = tid >> 6;
    const int lr = l & 15, lg = l >> 4;
    const int wbase = w * 32;
    const int sw = lr & 7;
    f32x4 acc[2][8];
    const f32x4 z4 = {0.f, 0.f, 0.f, 0.f};
#pragma unroll
    for (int m = 0; m < 2; ++m)
#pragma unroll
        for (int n = 0; n < 8; ++n) acc[m][n] = z4;
#pragma unroll
    for (int kt = 0; kt < 4; ++kt) {
        const int pch = ((kt * 4 + lg) ^ sw) * 8;
        short8 a0 = *(const short8*)(A + (wbase + lr) * 128 + pch);
        short8 a1 = *(const short8*)(A + (wbase + 16 + lr) * 128 + pch);
#pragma unroll
        for (int n = 0; n < 8; ++n) {
            short8 b = Wp[(n * 4 + kt) * 64 + l];
            acc[0][n] = __builtin_amdgcn_mfma_f32_16x16x32_bf16(a0, b, acc[0][n], 0, 0, 0);
            acc[1][n] = __builtin_amdgcn_mfma_f32_16x16x32_bf16(a1, b, acc[1][n], 0, 0, 0);
        }
    }
#pragma unroll
    for (int n = 0; n < 8; ++n) {
        const int col = n * 16 + lr;
        const float bb = bias[col];
        const int cch = col >> 3, cof = col & 7;
#pragma unroll
        for (int m = 0; m < 2; ++m) {
#pragma unroll
            for (int r = 0; r < 4; ++r) {
                int row = wbase + m * 16 + lg * 4 + r;
                float t = fmaxf(acc[m][n][r] + bb, 0.f);
                D[row * 128 + ((cch ^ (row & 7)) * 8) + cof] = f2b(t);
            }
        }
    }
}

// Segmented pool of the LDS tile into pooled[g*384 + coloff + col].
__device__ __forceinline__ void pool_tile(const ushort* __restrict__ T,
                                          const int* __restrict__ batchl,
                                          float* __restrict__ pooled,
                                          int coloff, int tid) {
    int col = tid & 127, half = tid >> 7;
    int cch = col >> 3, cof = col & 7;
    float pacc = 0.f;
    int curg = -1;
    for (int r = half * 64; r < half * 64 + 64; ++r) {
        int g = batchl[r];
        if (g != curg) {
            if (curg >= 0) atomicAdd(&pooled[curg * 384 + coloff + col], pacc);
            curg = g;
            pacc = 0.f;
        }
        if (g >= 0) pacc += uf((uint)T[r * 128 + ((cch ^ (r & 7)) * 8) + cof] << 16);
    }
    if (curg >= 0) atomicAdd(&pooled[curg * 384 + coloff + col], pacc);
}

// ---------------------------------------------------------------------------
// Fused layer 1: h1 = relu(relu((x + agg(x)) @ W1 + b1) @ W2 + b2) + pool
// ---------------------------------------------------------------------------
__global__ __launch_bounds__(256) void fl1_k(const float* __restrict__ x,
                                             const int* __restrict__ batch,
                                             const int* __restrict__ row_start,
                                             const ushort* __restrict__ nbr,
                                             const float* __restrict__ W1, // 8x128
                                             const float* __restrict__ b1,
                                             const short8* __restrict__ Wp2,
                                             const float* __restrict__ b2,
                                             ushort* __restrict__ out,
                                             float* __restrict__ pooled, int nNodes) {
    __shared__ float hin[128][8];
    __shared__ __align__(16) ushort T[128 * 128];
    __shared__ int batchl[128];
    int t = threadIdx.x;
    int n0 = blockIdx.x * 128;
    if (t < 128) batchl[t] = (n0 + t < nNodes) ? batch[n0 + t] : -1;
    {   // gather-sum staging: 2 threads per row, unroll x8
        int r = t >> 1;
        int half = t & 1;
        int n = n0 + r;
        float4 v = make_float4(0.f, 0.f, 0.f, 0.f);
        if (n < nNodes) {
            v = *(const float4*)(x + (size_t)n * 8 + half * 4);
            int rs = row_start[n], re = row_start[n + 1];
            int p = rs;
#define AX(u) { v.x += u.x; v.y += u.y; v.z += u.z; v.w += u.w; }
            for (; p + 8 <= re; p += 8) {
                int s0 = nbr[p],     s1 = nbr[p + 1], s2 = nbr[p + 2], s3 = nbr[p + 3];
                int s4 = nbr[p + 4], s5 = nbr[p + 5], s6 = nbr[p + 6], s7 = nbr[p + 7];
                float4 u0 = *(const float4*)(x + (size_t)s0 * 8 + half * 4);
                float4 u1 = *(const float4*)(x + (size_t)s1 * 8 + half * 4);
                float4 u2 = *(const float4*)(x + (size_t)s2 * 8 + half * 4);
                float4 u3 = *(const float4*)(x + (size_t)s3 * 8 + half * 4);
                float4 u4 = *(const float4*)(x + (size_t)s4 * 8 + half * 4);
                float4 u5 = *(const float4*)(x + (size_t)s5 * 8 + half * 4);
                float4 u6 = *(const float4*)(x + (size_t)s6 * 8 + half * 4);
                float4 u7 = *(const float4*)(x + (size_t)s7 * 8 + half * 4);
                AX(u0) AX(u1) AX(u2) AX(u3) AX(u4) AX(u5) AX(u6) AX(u7)
            }
            for (; p < re; ++p) {
                int s = nbr[p];
                float4 u = *(const float4*)(x + (size_t)s * 8 + half * 4);
                AX(u)
            }
#undef AX
        }
        *(float4*)(&hin[r][half * 4]) = v;
    }
    __syncthreads();
    // MLP1 (8->128), bf16 result into swizzled T
    int tx = t & 15, ty = t >> 4;
    float w[8][8];
#pragma unroll
    for (int k = 0; k < 8; ++k) {
        float4 w0 = *(const float4*)(W1 + k * HD + tx * 8);
        float4 w1 = *(const float4*)(W1 + k * HD + tx * 8 + 4);
        w[k][0] = w0.x; w[k][1] = w0.y; w[k][2] = w0.z; w[k][3] = w0.w;
        w[k][4] = w1.x; w[k][5] = w1.y; w[k][6] = w1.z; w[k][7] = w1.w;
    }
    float4 c0 = *(const float4*)(b1 + tx * 8);
    float4 c1 = *(const float4*)(b1 + tx * 8 + 4);
    float bb[8] = {c0.x, c0.y, c0.z, c0.w, c1.x, c1.y, c1.z, c1.w};
#pragma unroll
    for (int i = 0; i < 8; ++i) {
        int r = ty * 8 + i;
        float4 a0 = *(const float4*)(&hin[r][0]);
        float4 a1 = *(const float4*)(&hin[r][4]);
        float a[8] = {a0.x, a0.y, a0.z, a0.w, a1.x, a1.y, a1.z, a1.w};
        short8 ov;
#pragma unroll
        for (int jj = 0; jj < 8; ++jj) {
            float acc = bb[jj];
#pragma unroll
            for (int k = 0; k < 8; ++k) acc += a[k] * w[k][jj];
            ov[jj] = (short)f2b(fmaxf(acc, 0.f));
        }
        *(short8*)(T + r * 128 + ((tx ^ (r & 7)) * 8)) = ov;
    }
    __syncthreads();
    gemm128(T, Wp2, b2, T, t);     // in-place, wave-private rows
    __syncthreads();
#pragma unroll
    for (int i = 0; i < 8; ++i) {
        int idx = i * 256 + t;
        int row = idx >> 4, ch = idx & 15;
        int n = n0 + row;
        if (n < nNodes) {
            short8 v = *(const short8*)(T + row * 128 + ((ch ^ (row & 7)) * 8));
            *(short8*)(out + (size_t)n * HD + ch * 8) = v;
        }
    }
    pool_tile(T, batchl, pooled, 0, t);
}

// ---------------------------------------------------------------------------
// Fused layer MLP (layers 2,3): out = relu(relu(A@W1+b1)@W2+b2) + pool.
// STORE=0 skips the global h-store (layer 3: pool is the only consumer).
// ---------------------------------------------------------------------------
template <int STORE>
__global__ __launch_bounds__(256) void fmm_k(const ushort* __restrict__ Ain,
                                             const int* __restrict__ batch,
                                             const short8* __restrict__ Wp1,
                                             const float* __restrict__ b1,
                                             const short8* __restrict__ Wp2,
                                             const float* __restrict__ b2,
                                             ushort* __restrict__ out,
                                             float* __restrict__ pooled,
                                             int coloff, int nNodes) {
    __shared__ __align__(16) ushort T[128 * 128];
    __shared__ int batchl[128];
    const int t = threadIdx.x;
    const int n0 = blockIdx.x * 128;
    if (t < 128) batchl[t] = (n0 + t < nNodes) ? batch[n0 + t] : -1;
#pragma unroll
    for (int i = 0; i < 8; ++i) {
        int idx = i * 256 + t;
        int row = idx >> 4, ch = idx & 15;
        short8 v = {0, 0, 0, 0, 0, 0, 0, 0};
        int n = n0 + row;
        if (n < nNodes) v = *(const short8*)(Ain + (size_t)n * HD + ch * 8);
        *(short8*)(T + row * 128 + ((ch ^ (row & 7)) * 8)) = v;
    }
    __syncthreads();
    gemm128(T, Wp1, b1, T, t);
    __syncthreads();
    gemm128(T, Wp2, b2, T, t);
    __syncthreads();
    if constexpr (STORE) {
#pragma unroll
        for (int i = 0; i < 8; ++i) {
            int idx = i * 256 + t;
            int row = idx >> 4, ch = idx & 15;
            int n = n0 + row;
            if (n < nNodes) {
                short8 v = *(const short8*)(T + row * 128 + ((ch ^ (row & 7)) * 8));
                *(short8*)(out + (size_t)n * HD + ch * 8) = v;
            }
        }
    }
    pool_tile(T, batchl, pooled, coloff, t);
}

// ---------------------------------------------------------------------------
// Classifier (all fp32)
// ---------------------------------------------------------------------------
__global__ __launch_bounds__(256) void cls_k(const float* __restrict__ pooled,
                                             const float* __restrict__ W1,  // 384x256
                                             const float* __restrict__ b1,
                                             const float* __restrict__ gamma,
                                             const float* __restrict__ beta,
                                             const float* __restrict__ mean,
                                             const float* __restrict__ var,
                                             const float* __restrict__ W2,  // 256x4
                                             const float* __restrict__ b2,
                                             float* __restrict__ out) {
    __shared__ float pg[384];
    __shared__ float z[256];
    int g = blockIdx.x, j = threadIdx.x;
    pg[j] = pooled[g * 384 + j];
    if (j < 128) pg[256 + j] = pooled[g * 384 + 256 + j];
    __syncthreads();
    float acc = b1[j];
    for (int k = 0; k < 384; ++k) acc += pg[k] * W1[k * 256 + j];
    acc = (acc - mean[j]) * rsqrtf(var[j] + 1e-5f) * gamma[j] + beta[j];
    z[j] = fmaxf(acc, 0.f);
    __syncthreads();
    if (j < 4) {
        float o = b2[j];
        for (int k = 0; k < 256; ++k) o += z[k] * W2[k * 4 + j];
        out[g * 4 + j] = o;
    }
}

// ---------------------------------------------------------------------------
extern "C" void kernel_launch(void* const* d_in, const int* in_sizes, int n_in,
                              void* d_out, int out_size, void* d_ws, size_t ws_size,
                              hipStream_t stream) {
    const int N = NNODES, E = NEDGES;
    const float* x     = (const float*)d_in[0];
    const int*   ei    = (const int*)d_in[1];
    const int*   batch = (const int*)d_in[2];
    const float* l1W1 = (const float*)d_in[3];
    const float* l1b1 = (const float*)d_in[4];
    const float* l1W2 = (const float*)d_in[5];
    const float* l1b2 = (const float*)d_in[6];
    const float* l2W1 = (const float*)d_in[7];
    const float* l2b1 = (const float*)d_in[8];
    const float* l2W2 = (const float*)d_in[9];
    const float* l2b2 = (const float*)d_in[10];
    const float* l3W1 = (const float*)d_in[11];
    const float* l3b1 = (const float*)d_in[12];
    const float* l3W2 = (const float*)d_in[13];
    const float* l3b2 = (const float*)d_in[14];
    const float* cW1  = (const float*)d_in[15];
    const float* cb1  = (const float*)d_in[16];
    const float* bnG  = (const float*)d_in[17];
    const float* bnB  = (const float*)d_in[18];
    const float* bnM  = (const float*)d_in[19];
    const float* bnV  = (const float*)d_in[20];
    const float* cW2  = (const float*)d_in[21];
    const float* cb2  = (const float*)d_in[22];

    const int* src = ei;
    const int* dst = ei + E;

    // ---- workspace layout ----
    char* wsp = (char*)d_ws;
    ushort* tmpb = (ushort*)wsp;  wsp += (size_t)N * HD * 2;
    ushort* h1   = (ushort*)wsp;  wsp += (size_t)N * HD * 2;
    ushort* h2   = (ushort*)wsp;  wsp += (size_t)N * HD * 2;
    float* pooled = (float*)wsp;  wsp += (size_t)64 * 384 * 4;
    ushort* wp    = (ushort*)wsp; wsp += (size_t)5 * 16384 * 2;
    int* count    = (int*)wsp;    wsp += (size_t)N * 4;
    int* row_tmp  = (int*)wsp;    wsp += (size_t)N * 4;
    int* blocksum = (int*)wsp;    wsp += 256 * 4;
    int* row_start = (int*)wsp;   wsp += (size_t)(N + 1) * 4;
    int* cur       = (int*)wsp;   wsp += (size_t)N * 4;
    ushort* nbr    = (ushort*)wsp; wsp += (size_t)E * 2;

    const int nB = (N + 255) / 256;              // 196
    // setup: weight pack + zero count/pooled, then CSR build (XCD-partitioned)
    wpinit_k<<<dim3(8, 5), 256, 0, stream>>>(l1W2, l2W1, l2W2, l3W1, l3W2,
                                             wp, count, pooled);
    phist_k<<<2048, 256, 0, stream>>>(dst, count, E);
    scan1_k<<<nB, 256, 0, stream>>>(count, row_tmp, blocksum, N);
    scan23_k<<<nB, 256, 0, stream>>>(count, row_tmp, blocksum, nB, row_start, cur, N, E);
    pscatter_k<<<2048, 256, 0, stream>>>(src, dst, cur, nbr, E);

    const short8* Wp0 = (const short8*)(wp);
    const short8* Wp1 = (const short8*)(wp + 16384);
    const short8* Wp2 = (const short8*)(wp + 2 * 16384);
    const short8* Wp3 = (const short8*)(wp + 3 * 16384);
    const short8* Wp4 = (const short8*)(wp + 4 * 16384);

    const int mb = (N + 127) / 128;              // 391 tiles
    const int ab = ((N + 1) / 2 * 64) / 256;     // 6250 blocks
    // layer 1 (gather + MLP1 + GEMM2 + pool fused)
    fl1_k<<<mb, 256, 0, stream>>>(x, batch, row_start, nbr, l1W1, l1b1, Wp0, l1b2,
                                  h1, pooled, N);
    // layer 2
    aggb_k<<<ab, 256, 0, stream>>>(h1, row_start, nbr, tmpb, N);
    fmm_k<1><<<mb, 256, 0, stream>>>(tmpb, batch, Wp1, l2b1, Wp2, l2b2, h2,
                                     pooled, 128, N);
    // layer 3 (no h3 store: pool is the only consumer)
    aggb_k<<<ab, 256, 0, stream>>>(h2, row_start, nbr, tmpb, N);
    fmm_k<0><<<mb, 256, 0, stream>>>(tmpb, batch, Wp3, l3b1, Wp4, l3b2, nullptr,
                                     pooled, 256, N);
    // classifier
    cls_k<<<NGRAPH, 256, 0, stream>>>(pooled, cW1, cb1, bnG, bnB, bnM, bnV, cW2, cb2,
                                      (float*)d_out);
}